// Round 1
// baseline (100.219 us; speedup 1.0000x reference)
//
#include <hip/hip_runtime.h>

#define BS 16
#define S  256
#define H  1024
#define T  32

// ws layout (floats): p1[BS*S*T] | p2[BS*S*T] | ps[BS*T]
#define P1_OFF 0
#define P2_OFF (BS * S * T)
#define PS_OFF (2 * BS * S * T)

// ---------------------------------------------------------------------------
// Kernel A: p1/p2 GEMM (blocks 0..255) + ps (block 256)
//   C(4096 x 64) = E(4096 x 1024) * W12^T, cols 0..31 -> p1 (W[t, 0:H]),
//   cols 32..63 -> p2 (W[t, H:2H]).
//   Tile: BM=16, BN=64, BK=64; 256 threads; each thread 2x2 outputs.
// ---------------------------------------------------------------------------
__global__ __launch_bounds__(256) void gemm_p12_ps(
    const float* __restrict__ seq, const float* __restrict__ E,
    const float* __restrict__ W, const float* __restrict__ bias,
    float* __restrict__ ws)
{
    const int tid = threadIdx.x;
    float* p1 = ws + P1_OFF;
    float* p2 = ws + P2_OFF;
    float* ps = ws + PS_OFF;

    if (blockIdx.x == 256) {
        // ---- ps[b,t] = seq[b,:] . W[t, 2H:3H] + bias[t], 512 outputs ----
        #pragma unroll
        for (int rep = 0; rep < 2; ++rep) {
            int o = tid + rep * 256;           // 0..511
            int bb = o >> 5, t = o & 31;
            const float4* sp = (const float4*)(seq + (size_t)bb * H);
            const float4* wp = (const float4*)(W + (size_t)t * (3 * H) + 2 * H);
            float acc = 0.f;
            #pragma unroll 8
            for (int k = 0; k < H / 4; ++k) {
                float4 a = sp[k], w = wp[k];
                acc += a.x * w.x + a.y * w.y + a.z * w.z + a.w * w.w;
            }
            ps[o] = acc + bias[t];
        }
        return;
    }

    __shared__ __align__(16) float Et[16][68];   // pad 68: <=2-way aliasing (free)
    __shared__ __align__(16) float Wt[64][68];

    const int m0 = blockIdx.x * 16;
    const int c2 = tid & 31;        // col pair: c2 (p1), c2+32 (p2)
    const int r2 = tid >> 5;        // row pair: 2*r2, 2*r2+1
    const int rA = 2 * r2, rB = rA + 1;

    float a00 = 0.f, a01 = 0.f, a10 = 0.f, a11 = 0.f;

    for (int k0 = 0; k0 < H; k0 += 64) {
        __syncthreads();  // previous iter's LDS reads done before overwrite
        // stage E tile: 16 rows x 64 cols = 256 float4, 1 per thread
        {
            int row = tid >> 4, c4 = tid & 15;
            float4 v = *(const float4*)(E + (size_t)(m0 + row) * H + k0 + c4 * 4);
            *(float4*)&Et[row][c4 * 4] = v;
        }
        // stage W tile: 64 rows x 64 cols = 1024 float4, 4 per thread
        #pragma unroll
        for (int j = 0; j < 4; ++j) {
            int f = tid + j * 256;
            int n = f >> 4, c4 = f & 15;
            const float* src = W + (size_t)(n & 31) * (3 * H) + ((n >> 5) ? H : 0)
                                 + k0 + c4 * 4;
            *(float4*)&Wt[n][c4 * 4] = *(const float4*)src;
        }
        __syncthreads();

        #pragma unroll
        for (int k4 = 0; k4 < 16; ++k4) {
            float4 ea = *(const float4*)&Et[rA][k4 * 4];
            float4 eb = *(const float4*)&Et[rB][k4 * 4];
            float4 wa = *(const float4*)&Wt[c2][k4 * 4];
            float4 wb = *(const float4*)&Wt[c2 + 32][k4 * 4];
            a00 += ea.x * wa.x + ea.y * wa.y + ea.z * wa.z + ea.w * wa.w;
            a01 += ea.x * wb.x + ea.y * wb.y + ea.z * wb.z + ea.w * wb.w;
            a10 += eb.x * wa.x + eb.y * wa.y + eb.z * wa.z + eb.w * wa.w;
            a11 += eb.x * wb.x + eb.y * wb.y + eb.z * wb.z + eb.w * wb.w;
        }
    }

    p1[(size_t)(m0 + rA) * T + c2] = a00;
    p2[(size_t)(m0 + rA) * T + c2] = a01;
    p1[(size_t)(m0 + rB) * T + c2] = a10;
    p2[(size_t)(m0 + rB) * T + c2] = a11;
}

// ---------------------------------------------------------------------------
// Kernel B: out[b,i,j,t] = p1[b,i,t] + ps[b,t] + p2[b,j,t]
//   One block per (b,i). Stream S*T = 8192 floats = 2048 float4 per block.
// ---------------------------------------------------------------------------
__global__ __launch_bounds__(256) void bcast_add(
    const float* __restrict__ ws, float* __restrict__ out)
{
    const float* p1 = ws + P1_OFF;
    const float* p2 = ws + P2_OFF;
    const float* ps = ws + PS_OFF;

    const int blk = blockIdx.x;
    const int b = blk >> 8;          // /S
    const int i = blk & 255;         // %S
    const int tid = threadIdx.x;

    __shared__ __align__(16) float s1[32];
    if (tid < 32) s1[tid] = p1[(size_t)(b * S + i) * T + tid] + ps[b * T + tid];
    __syncthreads();

    const int t4 = tid & 7;                       // constant across iters (256%8==0)
    const float4 s = *(const float4*)&s1[t4 * 4];
    const float4* p2v = (const float4*)p2 + (size_t)b * (S * T / 4);
    float4* ov = (float4*)out + (size_t)(b * S + i) * (S * T / 4);

    #pragma unroll
    for (int k = tid; k < S * T / 4; k += 256) {
        float4 v = p2v[k];
        float4 r;
        r.x = v.x + s.x; r.y = v.y + s.y; r.z = v.z + s.z; r.w = v.w + s.w;
        ov[k] = r;
    }
}

extern "C" void kernel_launch(void* const* d_in, const int* in_sizes, int n_in,
                              void* d_out, int out_size, void* d_ws, size_t ws_size,
                              hipStream_t stream)
{
    const float* seq  = (const float*)d_in[0];   // (16,1024)
    const float* E    = (const float*)d_in[1];   // (16,256,1024)
    const float* W    = (const float*)d_in[2];   // (32,3072)
    const float* bias = (const float*)d_in[3];   // (32,)
    // d_in[4] = entities_tags: unused by the reference.
    float* out = (float*)d_out;                  // (16,256,256,32) f32
    float* ws  = (float*)d_ws;                   // ~1.03 MB used

    gemm_p12_ps<<<257, 256, 0, stream>>>(seq, E, W, bias, ws);
    bcast_add<<<BS * S, 256, 0, stream>>>(ws, out);
}